// Round 2
// baseline (1511.096 us; speedup 1.0000x reference)
//
#include <hip/hip_runtime.h>

#define N_NODES 100000
#define N_EDGES 3200000
#define CH 256

// ---------------- workspace layout (bytes) ----------------
// deg      int[N_NODES]   @ 0
// off      int[N_NODES]   @ 524288
// cursor   int[N_NODES]   @ 1048576
// partial  int[128]       @ 1572864
// edge_src int[N_EDGES]   @ 2097152   (12.8 MB)

__global__ void count_deg_k(const int* __restrict__ dst, int* __restrict__ deg) {
    int e = blockIdx.x * 256 + threadIdx.x;
    if (e < N_EDGES) atomicAdd(&deg[dst[e]], 1);
}

__global__ void scan_partial_k(const int* __restrict__ deg, int* __restrict__ partial) {
    __shared__ int sm[256];
    int t = threadIdx.x;
    int base = blockIdx.x * 1024 + t * 4;
    int s = 0;
#pragma unroll
    for (int i = 0; i < 4; ++i) {
        int idx = base + i;
        if (idx < N_NODES) s += deg[idx];
    }
    sm[t] = s;
    __syncthreads();
    for (int st = 128; st > 0; st >>= 1) {
        if (t < st) sm[t] += sm[t + st];
        __syncthreads();
    }
    if (t == 0) partial[blockIdx.x] = sm[0];
}

__global__ void scan_serial_k(int* __restrict__ partial, int nb) {
    if (threadIdx.x == 0 && blockIdx.x == 0) {
        int run = 0;
        for (int i = 0; i < nb; ++i) {
            int v = partial[i];
            partial[i] = run;
            run += v;
        }
    }
}

__global__ void scan_final_k(const int* __restrict__ deg, const int* __restrict__ partial,
                             int* __restrict__ off, int* __restrict__ cursor) {
    __shared__ int sm[256];
    int t = threadIdx.x;
    int base = blockIdx.x * 1024 + t * 4;
    int v[4];
    int s = 0;
#pragma unroll
    for (int i = 0; i < 4; ++i) {
        int idx = base + i;
        v[i] = (idx < N_NODES) ? deg[idx] : 0;
        s += v[i];
    }
    sm[t] = s;
    __syncthreads();
    int pre = 0;
    for (int j = 0; j < 256; ++j) {
        int xv = sm[j];
        pre += (j < t) ? xv : 0;
    }
    int start = partial[blockIdx.x] + pre;
#pragma unroll
    for (int i = 0; i < 4; ++i) {
        int idx = base + i;
        if (idx < N_NODES) {
            off[idx] = start;
            cursor[idx] = start;
            start += v[i];
        }
    }
}

__global__ void bucket_k(const int* __restrict__ src, const int* __restrict__ dst,
                         int* __restrict__ cursor, int* __restrict__ edge_src) {
    int e = blockIdx.x * 256 + threadIdx.x;
    if (e < N_EDGES) {
        int d = dst[e];
        int pos = atomicAdd(&cursor[d], 1);
        edge_src[pos] = src[e];
    }
}

// one wave per node; lane holds float4 (4 channels): 64 lanes * 4 = 256 ch.
// 2-edge unroll with dual accumulators: breaks the FMA dep chain and keeps
// two 1 KB row-gathers in flight per wave.
__global__ void aggregate_k(const float* __restrict__ x, const int* __restrict__ edge_src,
                            const int* __restrict__ off, const int* __restrict__ deg,
                            float* __restrict__ m) {
    int wid = threadIdx.x >> 6;
    int lane = threadIdx.x & 63;
    int node = blockIdx.x * 4 + wid;  // grid = N_NODES/4 exactly
    int start = off[node];
    int d = deg[node];
    float4 acc0 = make_float4(0.f, 0.f, 0.f, 0.f);
    float4 acc1 = make_float4(0.f, 0.f, 0.f, 0.f);
    const float* xb = x + (size_t)lane * 4;
    int e = 0;
    for (; e + 2 <= d; e += 2) {
        int s0 = edge_src[start + e];
        int s1 = edge_src[start + e + 1];
        const float4 v0 = *reinterpret_cast<const float4*>(xb + (size_t)s0 * CH);
        const float4 v1 = *reinterpret_cast<const float4*>(xb + (size_t)s1 * CH);
        acc0.x += v0.x; acc0.y += v0.y; acc0.z += v0.z; acc0.w += v0.w;
        acc1.x += v1.x; acc1.y += v1.y; acc1.z += v1.z; acc1.w += v1.w;
    }
    if (e < d) {
        int s0 = edge_src[start + e];
        const float4 v0 = *reinterpret_cast<const float4*>(xb + (size_t)s0 * CH);
        acc0.x += v0.x; acc0.y += v0.y; acc0.z += v0.z; acc0.w += v0.w;
    }
    acc0.x += acc1.x; acc0.y += acc1.y; acc0.z += acc1.z; acc0.w += acc1.w;
    float inv = 1.0f / (float)(d > 0 ? d : 1);
    acc0.x *= inv; acc0.y *= inv; acc0.z *= inv; acc0.w *= inv;
    *reinterpret_cast<float4*>(m + (size_t)node * CH + lane * 4) = acc0;
}

// in-place: io holds m (aggregated means); overwritten with m@W + bias*[deg>0].
// K chunked in 4 slices of 64: LDS tile As[64][68] = 17.4 KB (stride 68 floats
// -> row spacing 272 B = 16 mod 32 banks -> worst 2-way aliasing, free).
// VGPR ~115 -> 4 waves/SIMD -> ~50% occupancy (vs 20% at the 64 KB tile).
__global__ __launch_bounds__(256) void gemm_k(float* __restrict__ io, const float* __restrict__ W,
                                              const float* __restrict__ bias,
                                              const int* __restrict__ deg) {
    __shared__ float As[64][68];
    int row0 = blockIdx.x * 64;
    int rows = N_NODES - row0;
    if (rows > 64) rows = 64;
    int tid = threadIdx.x;

    int cg = (tid & 15) * 16;  // 16 output cols
    int rg = (tid >> 4) * 4;   // 4 rows

    // loader mapping: 4 threads per row, each loads 4 float4 (64 cols/chunk)
    int lr = tid >> 2;   // 0..63
    int lk = tid & 3;    // 0..3

    float acc[4][16];
#pragma unroll
    for (int i = 0; i < 4; ++i)
#pragma unroll
        for (int j = 0; j < 16; ++j) acc[i][j] = 0.f;

    for (int ko = 0; ko < 4; ++ko) {
        if (ko) __syncthreads();
        if (lr < rows) {
            const float* srcp = io + (size_t)(row0 + lr) * CH + ko * 64;
#pragma unroll
            for (int j = 0; j < 4; ++j) {
                int c = lk * 4 + j * 16;
                *reinterpret_cast<float4*>(&As[lr][c]) =
                    *reinterpret_cast<const float4*>(srcp + c);
            }
        }
        __syncthreads();

        const float* wbase = W + (size_t)(ko * 64) * CH + cg;
#pragma unroll 4
        for (int k4 = 0; k4 < 16; ++k4) {
            float av[4][4];
#pragma unroll
            for (int i = 0; i < 4; ++i)
                *reinterpret_cast<float4*>(&av[i][0]) =
                    *reinterpret_cast<const float4*>(&As[rg + i][k4 * 4]);
#pragma unroll
            for (int kk = 0; kk < 4; ++kk) {
                const float* wrow = wbase + (size_t)(k4 * 4 + kk) * CH;
                float wv[16];
                *reinterpret_cast<float4*>(&wv[0])  = *reinterpret_cast<const float4*>(wrow + 0);
                *reinterpret_cast<float4*>(&wv[4])  = *reinterpret_cast<const float4*>(wrow + 4);
                *reinterpret_cast<float4*>(&wv[8])  = *reinterpret_cast<const float4*>(wrow + 8);
                *reinterpret_cast<float4*>(&wv[12]) = *reinterpret_cast<const float4*>(wrow + 12);
#pragma unroll
                for (int i = 0; i < 4; ++i)
#pragma unroll
                    for (int j = 0; j < 16; ++j)
                        acc[i][j] = fmaf(av[i][kk], wv[j], acc[i][j]);
            }
        }
    }

    float bv[16];
#pragma unroll
    for (int j = 0; j < 16; ++j) bv[j] = bias[cg + j];

#pragma unroll
    for (int i = 0; i < 4; ++i) {
        int r = rg + i;
        if (r < rows) {
            float bon = (deg[row0 + r] > 0) ? 1.f : 0.f;
            float o[16];
#pragma unroll
            for (int j = 0; j < 16; ++j) o[j] = acc[i][j] + bv[j] * bon;
            float* po = io + (size_t)(row0 + r) * CH + cg;
            *reinterpret_cast<float4*>(po + 0)  = *reinterpret_cast<float4*>(&o[0]);
            *reinterpret_cast<float4*>(po + 4)  = *reinterpret_cast<float4*>(&o[4]);
            *reinterpret_cast<float4*>(po + 8)  = *reinterpret_cast<float4*>(&o[8]);
            *reinterpret_cast<float4*>(po + 12) = *reinterpret_cast<float4*>(&o[12]);
        }
    }
}

extern "C" void kernel_launch(void* const* d_in, const int* in_sizes, int n_in,
                              void* d_out, int out_size, void* d_ws, size_t ws_size,
                              hipStream_t stream) {
    const float* x    = (const float*)d_in[0];
    const int*   src  = (const int*)d_in[1];
    const int*   dst  = (const int*)d_in[2];
    const float* W    = (const float*)d_in[3];
    const float* bias = (const float*)d_in[4];
    float* out = (float*)d_out;

    char* ws = (char*)d_ws;
    int* deg      = (int*)(ws + 0);
    int* off      = (int*)(ws + 524288);
    int* cursor   = (int*)(ws + 1048576);
    int* partial  = (int*)(ws + 1572864);
    int* edge_src = (int*)(ws + 2097152);

    hipMemsetAsync(deg, 0, N_NODES * sizeof(int), stream);

    count_deg_k<<<(N_EDGES + 255) / 256, 256, 0, stream>>>(dst, deg);

    const int NB = (N_NODES + 1023) / 1024;  // 98
    scan_partial_k<<<NB, 256, 0, stream>>>(deg, partial);
    scan_serial_k<<<1, 64, 0, stream>>>(partial, NB);
    scan_final_k<<<NB, 256, 0, stream>>>(deg, partial, off, cursor);

    bucket_k<<<(N_EDGES + 255) / 256, 256, 0, stream>>>(src, dst, cursor, edge_src);

    aggregate_k<<<N_NODES / 4, 256, 0, stream>>>(x, edge_src, off, deg, out);

    gemm_k<<<(N_NODES + 63) / 64, 256, 0, stream>>>(out, W, bias, deg);
}

// Round 3
// 867.848 us; speedup vs baseline: 1.7412x; 1.7412x over previous
//
#include <hip/hip_runtime.h>

#define N_NODES 100000
#define N_EDGES 3200000
#define CH 256

// ---------------- workspace layout (bytes) ----------------
// deg      int[N_NODES]      @ 0
// off      int[N_NODES]      @ 524288
// cursor   int[N_NODES]      @ 1048576
// partial  int[128]          @ 1572864
// edge_src int[N_EDGES]      @ 2097152    (12.8 MB)
// Wtb      ushort[256*256]   @ 14897152   (128 KB)  W^T in bf16, [n][k]
// xb       ushort[N*CH]      @ 15028224   (51.2 MB) x in bf16 (optional)
#define WS_WTB   14897152
#define WS_XB    15028224
#define WS_NEED_BF16X (WS_XB + (size_t)N_NODES * CH * 2)

typedef __bf16  bf16x8 __attribute__((ext_vector_type(8)));
typedef float   f32x4  __attribute__((ext_vector_type(4)));

__device__ __forceinline__ unsigned short f2bf(float f) {
    union { float f; unsigned u; } c; c.f = f;
    unsigned r = c.u + 0x7FFF + ((c.u >> 16) & 1);  // RNE, finite inputs
    return (unsigned short)(r >> 16);
}
__device__ __forceinline__ float bf2f(unsigned short b) {
    union { unsigned u; float f; } c; c.u = (unsigned)b << 16;
    return c.f;
}

__global__ void count_deg_k(const int* __restrict__ dst, int* __restrict__ deg) {
    int e = blockIdx.x * 256 + threadIdx.x;
    if (e < N_EDGES) atomicAdd(&deg[dst[e]], 1);
}

__global__ void scan_partial_k(const int* __restrict__ deg, int* __restrict__ partial) {
    __shared__ int sm[256];
    int t = threadIdx.x;
    int base = blockIdx.x * 1024 + t * 4;
    int s = 0;
#pragma unroll
    for (int i = 0; i < 4; ++i) {
        int idx = base + i;
        if (idx < N_NODES) s += deg[idx];
    }
    sm[t] = s;
    __syncthreads();
    for (int st = 128; st > 0; st >>= 1) {
        if (t < st) sm[t] += sm[t + st];
        __syncthreads();
    }
    if (t == 0) partial[blockIdx.x] = sm[0];
}

__global__ void scan_serial_k(int* __restrict__ partial, int nb) {
    if (threadIdx.x == 0 && blockIdx.x == 0) {
        int run = 0;
        for (int i = 0; i < nb; ++i) {
            int v = partial[i];
            partial[i] = run;
            run += v;
        }
    }
}

__global__ void scan_final_k(const int* __restrict__ deg, const int* __restrict__ partial,
                             int* __restrict__ off, int* __restrict__ cursor) {
    __shared__ int sm[256];
    int t = threadIdx.x;
    int base = blockIdx.x * 1024 + t * 4;
    int v[4];
    int s = 0;
#pragma unroll
    for (int i = 0; i < 4; ++i) {
        int idx = base + i;
        v[i] = (idx < N_NODES) ? deg[idx] : 0;
        s += v[i];
    }
    sm[t] = s;
    __syncthreads();
    int pre = 0;
    for (int j = 0; j < 256; ++j) {
        int xv = sm[j];
        pre += (j < t) ? xv : 0;
    }
    int start = partial[blockIdx.x] + pre;
#pragma unroll
    for (int i = 0; i < 4; ++i) {
        int idx = base + i;
        if (idx < N_NODES) {
            off[idx] = start;
            cursor[idx] = start;
            start += v[i];
        }
    }
}

__global__ void bucket_k(const int* __restrict__ src, const int* __restrict__ dst,
                         int* __restrict__ cursor, int* __restrict__ edge_src) {
    int e = blockIdx.x * 256 + threadIdx.x;
    if (e < N_EDGES) {
        int d = dst[e];
        int pos = atomicAdd(&cursor[d], 1);
        edge_src[pos] = src[e];
    }
}

// W[k][n] fp32 -> Wtb[n][k] bf16. 256x256, one-time ~µs.
__global__ void cast_w_k(const float* __restrict__ W, unsigned short* __restrict__ Wtb) {
    int n = blockIdx.x;
    int k = threadIdx.x;
    Wtb[n * 256 + k] = f2bf(W[k * 256 + n]);
}

// x fp32 -> bf16, vectorized float4 -> ushort4. 6.4M float4 / 25000 blocks.
__global__ void cast_x_k(const float* __restrict__ x, unsigned short* __restrict__ xb) {
    int i = blockIdx.x * 256 + threadIdx.x;
    float4 v = reinterpret_cast<const float4*>(x)[i];
    ushort4 o;
    o.x = f2bf(v.x); o.y = f2bf(v.y); o.z = f2bf(v.z); o.w = f2bf(v.w);
    reinterpret_cast<ushort4*>(xb)[i] = o;
}

// one wave per node; lane holds 4 channels. bf16 gather (8 B/lane/edge),
// fp32 accumulate, 4-edge unroll / 4 acc sets for outstanding loads.
__global__ void aggregate_bf16_k(const unsigned short* __restrict__ xb,
                                 const int* __restrict__ edge_src,
                                 const int* __restrict__ off, const int* __restrict__ deg,
                                 float* __restrict__ m) {
    int wid = threadIdx.x >> 6;
    int lane = threadIdx.x & 63;
    int node = blockIdx.x * 4 + wid;
    int start = off[node];
    int d = deg[node];
    float4 acc[4];
#pragma unroll
    for (int i = 0; i < 4; ++i) acc[i] = make_float4(0.f, 0.f, 0.f, 0.f);
    const unsigned short* xbl = xb + lane * 4;
    int e = 0;
    for (; e + 4 <= d; e += 4) {
        int s[4];
#pragma unroll
        for (int i = 0; i < 4; ++i) s[i] = edge_src[start + e + i];
#pragma unroll
        for (int i = 0; i < 4; ++i) {
            ushort4 v = *reinterpret_cast<const ushort4*>(xbl + (size_t)s[i] * CH);
            acc[i].x += bf2f(v.x); acc[i].y += bf2f(v.y);
            acc[i].z += bf2f(v.z); acc[i].w += bf2f(v.w);
        }
    }
    for (; e < d; ++e) {
        int s0 = edge_src[start + e];
        ushort4 v = *reinterpret_cast<const ushort4*>(xbl + (size_t)s0 * CH);
        acc[0].x += bf2f(v.x); acc[0].y += bf2f(v.y);
        acc[0].z += bf2f(v.z); acc[0].w += bf2f(v.w);
    }
    acc[0].x += acc[1].x + acc[2].x + acc[3].x;
    acc[0].y += acc[1].y + acc[2].y + acc[3].y;
    acc[0].z += acc[1].z + acc[2].z + acc[3].z;
    acc[0].w += acc[1].w + acc[2].w + acc[3].w;
    float inv = 1.0f / (float)(d > 0 ? d : 1);
    acc[0].x *= inv; acc[0].y *= inv; acc[0].z *= inv; acc[0].w *= inv;
    *reinterpret_cast<float4*>(m + (size_t)node * CH + lane * 4) = acc[0];
}

// fp32 gather fallback (if ws too small for xb)
__global__ void aggregate_f32_k(const float* __restrict__ x, const int* __restrict__ edge_src,
                                const int* __restrict__ off, const int* __restrict__ deg,
                                float* __restrict__ m) {
    int wid = threadIdx.x >> 6;
    int lane = threadIdx.x & 63;
    int node = blockIdx.x * 4 + wid;
    int start = off[node];
    int d = deg[node];
    float4 acc0 = make_float4(0.f, 0.f, 0.f, 0.f);
    float4 acc1 = make_float4(0.f, 0.f, 0.f, 0.f);
    const float* xb = x + (size_t)lane * 4;
    int e = 0;
    for (; e + 2 <= d; e += 2) {
        int s0 = edge_src[start + e];
        int s1 = edge_src[start + e + 1];
        const float4 v0 = *reinterpret_cast<const float4*>(xb + (size_t)s0 * CH);
        const float4 v1 = *reinterpret_cast<const float4*>(xb + (size_t)s1 * CH);
        acc0.x += v0.x; acc0.y += v0.y; acc0.z += v0.z; acc0.w += v0.w;
        acc1.x += v1.x; acc1.y += v1.y; acc1.z += v1.z; acc1.w += v1.w;
    }
    if (e < d) {
        int s0 = edge_src[start + e];
        const float4 v0 = *reinterpret_cast<const float4*>(xb + (size_t)s0 * CH);
        acc0.x += v0.x; acc0.y += v0.y; acc0.z += v0.z; acc0.w += v0.w;
    }
    acc0.x += acc1.x; acc0.y += acc1.y; acc0.z += acc1.z; acc0.w += acc1.w;
    float inv = 1.0f / (float)(d > 0 ? d : 1);
    acc0.x *= inv; acc0.y *= inv; acc0.z *= inv; acc0.w *= inv;
    *reinterpret_cast<float4*>(m + (size_t)node * CH + lane * 4) = acc0;
}

// MFMA bf16 GEMM, in-place on io (fp32 means -> fp32 out).
// Block: 256 thr = 4 waves; tile 64 rows x 256 cols (wave w owns cols 64w..64w+63).
// A: fp32 tile converted to bf16 in LDS As[64][264] (stride 528 B -> 2-way bank
// alias only). B: Wtb[n][k] bf16 read from global (128 KB, L2-resident).
// 16x16x32 MFMA; A-frag lane l: A[m=l&15][k=8*(l>>4)+j]; B-frag: B[k][n=l&15];
// C/D: row=(l>>4)*4+r, col=l&15.
__global__ __launch_bounds__(256) void gemm_mfma_k(float* __restrict__ io,
                                                   const unsigned short* __restrict__ Wtb,
                                                   const float* __restrict__ bias,
                                                   const int* __restrict__ deg) {
    __shared__ unsigned short As[64][264];
    int row0 = blockIdx.x * 64;
    int rows = N_NODES - row0;
    if (rows > 64) rows = 64;
    int tid = threadIdx.x;

    // stage: 4096 float4 in the 64x256 tile; thread t takes f = i*256+t
#pragma unroll
    for (int i = 0; i < 16; ++i) {
        int f = i * 256 + tid;
        int r = f >> 6;
        int c4 = (f & 63) * 4;
        float4 v = make_float4(0.f, 0.f, 0.f, 0.f);
        if (r < rows)
            v = *reinterpret_cast<const float4*>(io + (size_t)(row0 + r) * CH + c4);
        ushort4 o;
        o.x = f2bf(v.x); o.y = f2bf(v.y); o.z = f2bf(v.z); o.w = f2bf(v.w);
        *reinterpret_cast<ushort4*>(&As[r][c4]) = o;
    }
    __syncthreads();

    int wv = tid >> 6;
    int lane = tid & 63;
    int q = lane >> 4;
    int ln = lane & 15;
    int n0 = wv * 64;

    f32x4 acc[4][4];
#pragma unroll
    for (int mt = 0; mt < 4; ++mt)
#pragma unroll
        for (int nt = 0; nt < 4; ++nt)
            acc[mt][nt] = (f32x4){0.f, 0.f, 0.f, 0.f};

#pragma unroll 2
    for (int kc = 0; kc < 8; ++kc) {
        int koff = kc * 32 + q * 8;
        bf16x8 a[4], b[4];
#pragma unroll
        for (int mt = 0; mt < 4; ++mt)
            a[mt] = *reinterpret_cast<const bf16x8*>(&As[mt * 16 + ln][koff]);
#pragma unroll
        for (int nt = 0; nt < 4; ++nt)
            b[nt] = *reinterpret_cast<const bf16x8*>(Wtb + (size_t)(n0 + nt * 16 + ln) * 256 + koff);
#pragma unroll
        for (int mt = 0; mt < 4; ++mt)
#pragma unroll
            for (int nt = 0; nt < 4; ++nt)
                acc[mt][nt] = __builtin_amdgcn_mfma_f32_16x16x32_bf16(a[mt], b[nt], acc[mt][nt], 0, 0, 0);
    }

    float bv[4];
#pragma unroll
    for (int nt = 0; nt < 4; ++nt) bv[nt] = bias[n0 + nt * 16 + ln];

#pragma unroll
    for (int mt = 0; mt < 4; ++mt) {
#pragma unroll
        for (int r = 0; r < 4; ++r) {
            int row = row0 + mt * 16 + q * 4 + r;
            if (row < N_NODES) {
                float bon = (deg[row] > 0) ? 1.f : 0.f;
                float* po = io + (size_t)row * CH + n0 + ln;
#pragma unroll
                for (int nt = 0; nt < 4; ++nt)
                    po[nt * 16] = acc[mt][nt][r] + bv[nt] * bon;
            }
        }
    }
}

extern "C" void kernel_launch(void* const* d_in, const int* in_sizes, int n_in,
                              void* d_out, int out_size, void* d_ws, size_t ws_size,
                              hipStream_t stream) {
    const float* x    = (const float*)d_in[0];
    const int*   src  = (const int*)d_in[1];
    const int*   dst  = (const int*)d_in[2];
    const float* W    = (const float*)d_in[3];
    const float* bias = (const float*)d_in[4];
    float* out = (float*)d_out;

    char* ws = (char*)d_ws;
    int* deg      = (int*)(ws + 0);
    int* off      = (int*)(ws + 524288);
    int* cursor   = (int*)(ws + 1048576);
    int* partial  = (int*)(ws + 1572864);
    int* edge_src = (int*)(ws + 2097152);
    unsigned short* Wtb = (unsigned short*)(ws + WS_WTB);
    unsigned short* xb  = (unsigned short*)(ws + WS_XB);

    bool use_bf16x = ws_size >= WS_NEED_BF16X;

    hipMemsetAsync(deg, 0, N_NODES * sizeof(int), stream);

    count_deg_k<<<(N_EDGES + 255) / 256, 256, 0, stream>>>(dst, deg);

    const int NB = (N_NODES + 1023) / 1024;  // 98
    scan_partial_k<<<NB, 256, 0, stream>>>(deg, partial);
    scan_serial_k<<<1, 64, 0, stream>>>(partial, NB);
    scan_final_k<<<NB, 256, 0, stream>>>(deg, partial, off, cursor);

    bucket_k<<<(N_EDGES + 255) / 256, 256, 0, stream>>>(src, dst, cursor, edge_src);

    cast_w_k<<<256, 256, 0, stream>>>(W, Wtb);

    if (use_bf16x) {
        cast_x_k<<<(N_NODES * CH / 4) / 256, 256, 0, stream>>>(x, xb);
        aggregate_bf16_k<<<N_NODES / 4, 256, 0, stream>>>(xb, edge_src, off, deg, out);
    } else {
        aggregate_f32_k<<<N_NODES / 4, 256, 0, stream>>>(x, edge_src, off, deg, out);
    }

    gemm_mfma_k<<<(N_NODES + 63) / 64, 256, 0, stream>>>(out, Wtb, bias, deg);
}

// Round 4
// 568.596 us; speedup vs baseline: 2.6576x; 1.5263x over previous
//
#include <hip/hip_runtime.h>

#define N_NODES 100000
#define N_EDGES 3200000
#define CH 256

#define NBUCK 256          // dst >> 9 ; max bucket = 99999>>9 = 195
#define NBUCK_USED 196
#define PBE 4096           // edges per partition block
#define EPT 16             // edges per thread (256 thr)
#define PGRID ((N_EDGES + PBE - 1) / PBE)   // 782

// ---------------- workspace layout (bytes) ----------------
// deg        int[N_NODES]     @ 0          (512 KB)
// off        int[N_NODES]     @ 524288     (512 KB)
// bucket_cnt int[256]         @ 1048576
// bucket_base int[256]        @ 1049600
// bucket_cur int[256]         @ 1050624
// Wtb        ushort[256*256]  @ 1056768    (128 KB)
// edge_src   int[N_EDGES]     @ 1310720    (12.8 MB)
// packed     uint[N_EDGES]    @ 14110720   (12.8 MB)  dead after build_k
// xb         ushort[N*CH]     @ 14110720   (51.2 MB)  ALIASES packed; cast_x runs after build_k
#define WS_DEG    0
#define WS_OFF    524288
#define WS_BCNT   1048576
#define WS_BBASE  1049600
#define WS_BCUR   1050624
#define WS_WTB    1056768
#define WS_ESRC   1310720
#define WS_PACKED 14110720
#define WS_XB     14110720
#define WS_NEED_BF16X (WS_XB + (size_t)N_NODES * CH * 2)   // 65.3 MB

typedef __bf16  bf16x8 __attribute__((ext_vector_type(8)));
typedef float   f32x4  __attribute__((ext_vector_type(4)));

__device__ __forceinline__ unsigned short f2bf(float f) {
    union { float f; unsigned u; } c; c.f = f;
    unsigned r = c.u + 0x7FFF + ((c.u >> 16) & 1);  // RNE, finite inputs
    return (unsigned short)(r >> 16);
}
__device__ __forceinline__ float bf2f(unsigned short b) {
    union { unsigned u; float f; } c; c.u = (unsigned)b << 16;
    return c.f;
}

// per-block LDS histogram of dst>>9; one global atomic per (block,bin)
__global__ __launch_bounds__(256) void hist_k(const int* __restrict__ dst,
                                              int* __restrict__ bucket_cnt) {
    __shared__ int h[NBUCK];
    int t = threadIdx.x;
    h[t] = 0;
    __syncthreads();
    long e0 = (long)blockIdx.x * PBE;
#pragma unroll
    for (int i = 0; i < EPT; ++i) {
        long e = e0 + i * 256 + t;
        if (e < N_EDGES) atomicAdd(&h[dst[e] >> 9], 1);
    }
    __syncthreads();
    if (h[t]) atomicAdd(&bucket_cnt[t], h[t]);
}

// exclusive scan of 256 bucket counts -> base and cursor
__global__ void bscan_k(const int* __restrict__ cnt, int* __restrict__ base,
                        int* __restrict__ cursor) {
    __shared__ int s[NBUCK];
    int t = threadIdx.x;
    int v0 = cnt[t];
    s[t] = v0;
    __syncthreads();
    for (int st = 1; st < 256; st <<= 1) {
        int v = (t >= st) ? s[t - st] : 0;
        __syncthreads();
        s[t] += v;
        __syncthreads();
    }
    int excl = s[t] - v0;
    base[t] = excl;
    cursor[t] = excl;
}

// rank edges per bucket in LDS, reserve one contiguous global run per
// (block,bucket), write packed (dlow<<17 | src). Block writes land in 256
// dense runs (L2-resident, full-line) instead of 3.2M random 4B stores.
__global__ __launch_bounds__(256) void partition_k(const int* __restrict__ src,
                                                   const int* __restrict__ dst,
                                                   int* __restrict__ bucket_cursor,
                                                   unsigned* __restrict__ packed) {
    __shared__ int hist[NBUCK];
    __shared__ int gbase[NBUCK];
    int t = threadIdx.x;
    hist[t] = 0;
    __syncthreads();
    long e0 = (long)blockIdx.x * PBE;
    int b[EPT], rank[EPT];
    unsigned pk[EPT];
#pragma unroll
    for (int i = 0; i < EPT; ++i) {
        long e = e0 + i * 256 + t;
        if (e < N_EDGES) {
            int d = dst[e];
            int s = src[e];
            b[i] = d >> 9;
            pk[i] = ((unsigned)(d & 511) << 17) | (unsigned)s;
            rank[i] = atomicAdd(&hist[b[i]], 1);
        } else b[i] = -1;
    }
    __syncthreads();
    int cnt = hist[t];
    if (cnt > 0) gbase[t] = atomicAdd(&bucket_cursor[t], cnt);
    __syncthreads();
#pragma unroll
    for (int i = 0; i < EPT; ++i)
        if (b[i] >= 0) packed[gbase[b[i]] + rank[i]] = pk[i];
}

// one block per bucket: all 512 node cursors + the bucket's edges are
// L2/LDS-local. Produces deg, off (global CSR offsets) and edge_src, with
// zero global atomics and scatter confined to a 65 KB window.
__global__ __launch_bounds__(256) void build_k(const unsigned* __restrict__ packed,
                                               const int* __restrict__ bucket_base,
                                               const int* __restrict__ bucket_cnt,
                                               int* __restrict__ deg, int* __restrict__ off,
                                               int* __restrict__ edge_src) {
    __shared__ int ldeg[512];
    __shared__ int loff[512];
    __shared__ int lcur[512];
    __shared__ int sscan[256];
    int bk = blockIdx.x;
    int t = threadIdx.x;
    ldeg[t] = 0; ldeg[t + 256] = 0;
    __syncthreads();
    int ebase = bucket_base[bk];
    int ecnt  = bucket_cnt[bk];
    const unsigned* pk = packed + ebase;
    for (int i = t; i < ecnt; i += 256) atomicAdd(&ldeg[pk[i] >> 17], 1);
    __syncthreads();
    int a0 = ldeg[2 * t], a1 = ldeg[2 * t + 1];
    sscan[t] = a0 + a1;
    __syncthreads();
    for (int st = 1; st < 256; st <<= 1) {
        int v = (t >= st) ? sscan[t - st] : 0;
        __syncthreads();
        sscan[t] += v;
        __syncthreads();
    }
    int ex = sscan[t] - (a0 + a1);
    loff[2 * t] = ex;      lcur[2 * t] = ex;
    loff[2 * t + 1] = ex + a0;  lcur[2 * t + 1] = ex + a0;
    __syncthreads();
    int n0 = bk * 512;
#pragma unroll
    for (int j = 0; j < 2; ++j) {
        int dlow = t + j * 256;
        int node = n0 + dlow;
        if (node < N_NODES) {
            deg[node] = ldeg[dlow];
            off[node] = ebase + loff[dlow];
        }
    }
    int* es = edge_src + ebase;
    for (int i = t; i < ecnt; i += 256) {
        unsigned p = pk[i];
        int pos = atomicAdd(&lcur[p >> 17], 1);
        es[pos] = (int)(p & 0x1FFFF);
    }
}

// W[k][n] fp32 -> Wtb[n][k] bf16
__global__ void cast_w_k(const float* __restrict__ W, unsigned short* __restrict__ Wtb) {
    int n = blockIdx.x;
    int k = threadIdx.x;
    Wtb[n * 256 + k] = f2bf(W[k * 256 + n]);
}

// x fp32 -> bf16 (runs AFTER build_k: xb aliases packed)
__global__ void cast_x_k(const float* __restrict__ x, unsigned short* __restrict__ xb) {
    int i = blockIdx.x * 256 + threadIdx.x;
    float4 v = reinterpret_cast<const float4*>(x)[i];
    ushort4 o;
    o.x = f2bf(v.x); o.y = f2bf(v.y); o.z = f2bf(v.z); o.w = f2bf(v.w);
    reinterpret_cast<ushort4*>(xb)[i] = o;
}

// one wave per node; lane holds 4 channels; bf16 gather, fp32 accumulate
__global__ void aggregate_bf16_k(const unsigned short* __restrict__ xb,
                                 const int* __restrict__ edge_src,
                                 const int* __restrict__ off, const int* __restrict__ deg,
                                 float* __restrict__ m) {
    int wid = threadIdx.x >> 6;
    int lane = threadIdx.x & 63;
    int node = blockIdx.x * 4 + wid;
    int start = off[node];
    int d = deg[node];
    float4 acc[4];
#pragma unroll
    for (int i = 0; i < 4; ++i) acc[i] = make_float4(0.f, 0.f, 0.f, 0.f);
    const unsigned short* xbl = xb + lane * 4;
    int e = 0;
    for (; e + 4 <= d; e += 4) {
        int s[4];
#pragma unroll
        for (int i = 0; i < 4; ++i) s[i] = edge_src[start + e + i];
#pragma unroll
        for (int i = 0; i < 4; ++i) {
            ushort4 v = *reinterpret_cast<const ushort4*>(xbl + (size_t)s[i] * CH);
            acc[i].x += bf2f(v.x); acc[i].y += bf2f(v.y);
            acc[i].z += bf2f(v.z); acc[i].w += bf2f(v.w);
        }
    }
    for (; e < d; ++e) {
        int s0 = edge_src[start + e];
        ushort4 v = *reinterpret_cast<const ushort4*>(xbl + (size_t)s0 * CH);
        acc[0].x += bf2f(v.x); acc[0].y += bf2f(v.y);
        acc[0].z += bf2f(v.z); acc[0].w += bf2f(v.w);
    }
    acc[0].x += acc[1].x + acc[2].x + acc[3].x;
    acc[0].y += acc[1].y + acc[2].y + acc[3].y;
    acc[0].z += acc[1].z + acc[2].z + acc[3].z;
    acc[0].w += acc[1].w + acc[2].w + acc[3].w;
    float inv = 1.0f / (float)(d > 0 ? d : 1);
    acc[0].x *= inv; acc[0].y *= inv; acc[0].z *= inv; acc[0].w *= inv;
    *reinterpret_cast<float4*>(m + (size_t)node * CH + lane * 4) = acc[0];
}

// fp32 gather fallback (if ws too small for xb)
__global__ void aggregate_f32_k(const float* __restrict__ x, const int* __restrict__ edge_src,
                                const int* __restrict__ off, const int* __restrict__ deg,
                                float* __restrict__ m) {
    int wid = threadIdx.x >> 6;
    int lane = threadIdx.x & 63;
    int node = blockIdx.x * 4 + wid;
    int start = off[node];
    int d = deg[node];
    float4 acc0 = make_float4(0.f, 0.f, 0.f, 0.f);
    float4 acc1 = make_float4(0.f, 0.f, 0.f, 0.f);
    const float* xb = x + (size_t)lane * 4;
    int e = 0;
    for (; e + 2 <= d; e += 2) {
        int s0 = edge_src[start + e];
        int s1 = edge_src[start + e + 1];
        const float4 v0 = *reinterpret_cast<const float4*>(xb + (size_t)s0 * CH);
        const float4 v1 = *reinterpret_cast<const float4*>(xb + (size_t)s1 * CH);
        acc0.x += v0.x; acc0.y += v0.y; acc0.z += v0.z; acc0.w += v0.w;
        acc1.x += v1.x; acc1.y += v1.y; acc1.z += v1.z; acc1.w += v1.w;
    }
    if (e < d) {
        int s0 = edge_src[start + e];
        const float4 v0 = *reinterpret_cast<const float4*>(xb + (size_t)s0 * CH);
        acc0.x += v0.x; acc0.y += v0.y; acc0.z += v0.z; acc0.w += v0.w;
    }
    acc0.x += acc1.x; acc0.y += acc1.y; acc0.z += acc1.z; acc0.w += acc1.w;
    float inv = 1.0f / (float)(d > 0 ? d : 1);
    acc0.x *= inv; acc0.y *= inv; acc0.z *= inv; acc0.w *= inv;
    *reinterpret_cast<float4*>(m + (size_t)node * CH + lane * 4) = acc0;
}

// MFMA bf16 GEMM, in-place on io (fp32 means -> fp32 out). See round-3 notes.
__global__ __launch_bounds__(256) void gemm_mfma_k(float* __restrict__ io,
                                                   const unsigned short* __restrict__ Wtb,
                                                   const float* __restrict__ bias,
                                                   const int* __restrict__ deg) {
    __shared__ unsigned short As[64][264];
    int row0 = blockIdx.x * 64;
    int rows = N_NODES - row0;
    if (rows > 64) rows = 64;
    int tid = threadIdx.x;

#pragma unroll
    for (int i = 0; i < 16; ++i) {
        int f = i * 256 + tid;
        int r = f >> 6;
        int c4 = (f & 63) * 4;
        float4 v = make_float4(0.f, 0.f, 0.f, 0.f);
        if (r < rows)
            v = *reinterpret_cast<const float4*>(io + (size_t)(row0 + r) * CH + c4);
        ushort4 o;
        o.x = f2bf(v.x); o.y = f2bf(v.y); o.z = f2bf(v.z); o.w = f2bf(v.w);
        *reinterpret_cast<ushort4*>(&As[r][c4]) = o;
    }
    __syncthreads();

    int wv = tid >> 6;
    int lane = tid & 63;
    int q = lane >> 4;
    int ln = lane & 15;
    int n0 = wv * 64;

    f32x4 acc[4][4];
#pragma unroll
    for (int mt = 0; mt < 4; ++mt)
#pragma unroll
        for (int nt = 0; nt < 4; ++nt)
            acc[mt][nt] = (f32x4){0.f, 0.f, 0.f, 0.f};

#pragma unroll 2
    for (int kc = 0; kc < 8; ++kc) {
        int koff = kc * 32 + q * 8;
        bf16x8 a[4], b[4];
#pragma unroll
        for (int mt = 0; mt < 4; ++mt)
            a[mt] = *reinterpret_cast<const bf16x8*>(&As[mt * 16 + ln][koff]);
#pragma unroll
        for (int nt = 0; nt < 4; ++nt)
            b[nt] = *reinterpret_cast<const bf16x8*>(Wtb + (size_t)(n0 + nt * 16 + ln) * 256 + koff);
#pragma unroll
        for (int mt = 0; mt < 4; ++mt)
#pragma unroll
            for (int nt = 0; nt < 4; ++nt)
                acc[mt][nt] = __builtin_amdgcn_mfma_f32_16x16x32_bf16(a[mt], b[nt], acc[mt][nt], 0, 0, 0);
    }

    float bv[4];
#pragma unroll
    for (int nt = 0; nt < 4; ++nt) bv[nt] = bias[n0 + nt * 16 + ln];

#pragma unroll
    for (int mt = 0; mt < 4; ++mt) {
#pragma unroll
        for (int r = 0; r < 4; ++r) {
            int row = row0 + mt * 16 + q * 4 + r;
            if (row < N_NODES) {
                float bon = (deg[row] > 0) ? 1.f : 0.f;
                float* po = io + (size_t)row * CH + n0 + ln;
#pragma unroll
                for (int nt = 0; nt < 4; ++nt)
                    po[nt * 16] = acc[mt][nt][r] + bv[nt] * bon;
            }
        }
    }
}

extern "C" void kernel_launch(void* const* d_in, const int* in_sizes, int n_in,
                              void* d_out, int out_size, void* d_ws, size_t ws_size,
                              hipStream_t stream) {
    const float* x    = (const float*)d_in[0];
    const int*   src  = (const int*)d_in[1];
    const int*   dst  = (const int*)d_in[2];
    const float* W    = (const float*)d_in[3];
    const float* bias = (const float*)d_in[4];
    float* out = (float*)d_out;

    char* ws = (char*)d_ws;
    int* deg        = (int*)(ws + WS_DEG);
    int* off        = (int*)(ws + WS_OFF);
    int* bcnt       = (int*)(ws + WS_BCNT);
    int* bbase      = (int*)(ws + WS_BBASE);
    int* bcur       = (int*)(ws + WS_BCUR);
    unsigned short* Wtb = (unsigned short*)(ws + WS_WTB);
    int* edge_src   = (int*)(ws + WS_ESRC);
    unsigned* packed = (unsigned*)(ws + WS_PACKED);
    unsigned short* xb = (unsigned short*)(ws + WS_XB);  // aliases packed

    bool use_bf16x = ws_size >= WS_NEED_BF16X;

    hipMemsetAsync(bcnt, 0, NBUCK * sizeof(int), stream);

    hist_k<<<PGRID, 256, 0, stream>>>(dst, bcnt);
    bscan_k<<<1, 256, 0, stream>>>(bcnt, bbase, bcur);
    partition_k<<<PGRID, 256, 0, stream>>>(src, dst, bcur, packed);
    build_k<<<NBUCK_USED, 256, 0, stream>>>(packed, bbase, bcnt, deg, off, edge_src);

    cast_w_k<<<256, 256, 0, stream>>>(W, Wtb);

    if (use_bf16x) {
        cast_x_k<<<(N_NODES * CH / 4) / 256, 256, 0, stream>>>(x, xb);  // after build_k!
        aggregate_bf16_k<<<N_NODES / 4, 256, 0, stream>>>(xb, edge_src, off, deg, out);
    } else {
        aggregate_f32_k<<<N_NODES / 4, 256, 0, stream>>>(x, edge_src, off, deg, out);
    }

    gemm_mfma_k<<<(N_NODES + 63) / 64, 256, 0, stream>>>(out, Wtb, bias, deg);
}

// Round 5
// 560.783 us; speedup vs baseline: 2.6946x; 1.0139x over previous
//
#include <hip/hip_runtime.h>

#define N_NODES 100000
#define N_EDGES 3200000
#define CH 256

#define NBUCK 256          // dst >> 9 ; max bucket = 99999>>9 = 195
#define NBUCK_USED 196
#define PBE 4096           // edges per partition block
#define EPT 16             // edges per thread (256 thr)
#define PGRID ((N_EDGES + PBE - 1) / PBE)   // 782

// ---------------- workspace layout (bytes) ----------------
// deg        int[N_NODES]     @ 0          (512 KB)
// off        int[N_NODES]     @ 524288     (512 KB)
// bucket_cnt int[256]         @ 1048576
// bucket_base int[256]        @ 1049600
// bucket_cur int[256]         @ 1050624
// Wtb        ushort[256*256]  @ 1056768    (128 KB)
// edge_src   int[N_EDGES]     @ 1310720    (12.8 MB)
// packed     uint[N_EDGES]    @ 14110720   (12.8 MB)  dead after build_k
// hb         ushort[N*CH]     @ 14110720   (51.2 MB)  ALIASES packed; gemm_h runs after build_k
#define WS_DEG    0
#define WS_OFF    524288
#define WS_BCNT   1048576
#define WS_BBASE  1049600
#define WS_BCUR   1050624
#define WS_WTB    1056768
#define WS_ESRC   1310720
#define WS_PACKED 14110720
#define WS_HB     14110720
#define WS_NEED_H (WS_HB + (size_t)N_NODES * CH * 2)   // 65.3 MB

typedef __bf16  bf16x8 __attribute__((ext_vector_type(8)));
typedef float   f32x4  __attribute__((ext_vector_type(4)));

__device__ __forceinline__ unsigned short f2bf(float f) {
    union { float f; unsigned u; } c; c.f = f;
    unsigned r = c.u + 0x7FFF + ((c.u >> 16) & 1);  // RNE, finite inputs
    return (unsigned short)(r >> 16);
}
__device__ __forceinline__ float bf2f(unsigned short b) {
    union { unsigned u; float f; } c; c.u = (unsigned)b << 16;
    return c.f;
}

// per-block LDS histogram of dst>>9; one global atomic per (block,bin)
__global__ __launch_bounds__(256) void hist_k(const int* __restrict__ dst,
                                              int* __restrict__ bucket_cnt) {
    __shared__ int h[NBUCK];
    int t = threadIdx.x;
    h[t] = 0;
    __syncthreads();
    long e0 = (long)blockIdx.x * PBE;
#pragma unroll
    for (int i = 0; i < EPT; ++i) {
        long e = e0 + i * 256 + t;
        if (e < N_EDGES) atomicAdd(&h[dst[e] >> 9], 1);
    }
    __syncthreads();
    if (h[t]) atomicAdd(&bucket_cnt[t], h[t]);
}

// exclusive scan of 256 bucket counts -> base and cursor
__global__ void bscan_k(const int* __restrict__ cnt, int* __restrict__ base,
                        int* __restrict__ cursor) {
    __shared__ int s[NBUCK];
    int t = threadIdx.x;
    int v0 = cnt[t];
    s[t] = v0;
    __syncthreads();
    for (int st = 1; st < 256; st <<= 1) {
        int v = (t >= st) ? s[t - st] : 0;
        __syncthreads();
        s[t] += v;
        __syncthreads();
    }
    int excl = s[t] - v0;
    base[t] = excl;
    cursor[t] = excl;
}

// rank edges per bucket in LDS, reserve one contiguous global run per
// (block,bucket), write packed (dlow<<17 | src).
__global__ __launch_bounds__(256) void partition_k(const int* __restrict__ src,
                                                   const int* __restrict__ dst,
                                                   int* __restrict__ bucket_cursor,
                                                   unsigned* __restrict__ packed) {
    __shared__ int hist[NBUCK];
    __shared__ int gbase[NBUCK];
    int t = threadIdx.x;
    hist[t] = 0;
    __syncthreads();
    long e0 = (long)blockIdx.x * PBE;
    int b[EPT], rank[EPT];
    unsigned pk[EPT];
#pragma unroll
    for (int i = 0; i < EPT; ++i) {
        long e = e0 + i * 256 + t;
        if (e < N_EDGES) {
            int d = dst[e];
            int s = src[e];
            b[i] = d >> 9;
            pk[i] = ((unsigned)(d & 511) << 17) | (unsigned)s;
            rank[i] = atomicAdd(&hist[b[i]], 1);
        } else b[i] = -1;
    }
    __syncthreads();
    int cnt = hist[t];
    if (cnt > 0) gbase[t] = atomicAdd(&bucket_cursor[t], cnt);
    __syncthreads();
#pragma unroll
    for (int i = 0; i < EPT; ++i)
        if (b[i] >= 0) packed[gbase[b[i]] + rank[i]] = pk[i];
}

// one block per bucket: deg, off (global CSR) and edge_src, zero global atomics.
__global__ __launch_bounds__(256) void build_k(const unsigned* __restrict__ packed,
                                               const int* __restrict__ bucket_base,
                                               const int* __restrict__ bucket_cnt,
                                               int* __restrict__ deg, int* __restrict__ off,
                                               int* __restrict__ edge_src) {
    __shared__ int ldeg[512];
    __shared__ int loff[512];
    __shared__ int lcur[512];
    __shared__ int sscan[256];
    int bk = blockIdx.x;
    int t = threadIdx.x;
    ldeg[t] = 0; ldeg[t + 256] = 0;
    __syncthreads();
    int ebase = bucket_base[bk];
    int ecnt  = bucket_cnt[bk];
    const unsigned* pk = packed + ebase;
    for (int i = t; i < ecnt; i += 256) atomicAdd(&ldeg[pk[i] >> 17], 1);
    __syncthreads();
    int a0 = ldeg[2 * t], a1 = ldeg[2 * t + 1];
    sscan[t] = a0 + a1;
    __syncthreads();
    for (int st = 1; st < 256; st <<= 1) {
        int v = (t >= st) ? sscan[t - st] : 0;
        __syncthreads();
        sscan[t] += v;
        __syncthreads();
    }
    int ex = sscan[t] - (a0 + a1);
    loff[2 * t] = ex;      lcur[2 * t] = ex;
    loff[2 * t + 1] = ex + a0;  lcur[2 * t + 1] = ex + a0;
    __syncthreads();
    int n0 = bk * 512;
#pragma unroll
    for (int j = 0; j < 2; ++j) {
        int dlow = t + j * 256;
        int node = n0 + dlow;
        if (node < N_NODES) {
            deg[node] = ldeg[dlow];
            off[node] = ebase + loff[dlow];
        }
    }
    int* es = edge_src + ebase;
    for (int i = t; i < ecnt; i += 256) {
        unsigned p = pk[i];
        int pos = atomicAdd(&lcur[p >> 17], 1);
        es[pos] = (int)(p & 0x1FFFF);
    }
}

// W[k][n] fp32 -> Wtb[n][k] bf16
__global__ void cast_w_k(const float* __restrict__ W, unsigned short* __restrict__ Wtb) {
    int n = blockIdx.x;
    int k = threadIdx.x;
    Wtb[n * 256 + k] = f2bf(W[k * 256 + n]);
}

// h = x @ W + bias, output bf16. Block: 64 rows x 256 cols, 4 waves.
// A: x fp32 staged->bf16 LDS As[64][264]; B: Wtb[n][k] from L2.
// 16x16x32 MFMA; C/D: row=(l>>4)*4+r, col=l&15.
__global__ __launch_bounds__(256) void gemm_h_k(const float* __restrict__ x,
                                                const unsigned short* __restrict__ Wtb,
                                                const float* __restrict__ bias,
                                                unsigned short* __restrict__ hb) {
    __shared__ unsigned short As[64][264];
    int row0 = blockIdx.x * 64;
    int rows = N_NODES - row0;
    if (rows > 64) rows = 64;
    int tid = threadIdx.x;

#pragma unroll
    for (int i = 0; i < 16; ++i) {
        int f = i * 256 + tid;
        int r = f >> 6;
        int c4 = (f & 63) * 4;
        float4 v = make_float4(0.f, 0.f, 0.f, 0.f);
        if (r < rows)
            v = *reinterpret_cast<const float4*>(x + (size_t)(row0 + r) * CH + c4);
        ushort4 o;
        o.x = f2bf(v.x); o.y = f2bf(v.y); o.z = f2bf(v.z); o.w = f2bf(v.w);
        *reinterpret_cast<ushort4*>(&As[r][c4]) = o;
    }
    __syncthreads();

    int wv = tid >> 6;
    int lane = tid & 63;
    int q = lane >> 4;
    int ln = lane & 15;
    int n0 = wv * 64;

    f32x4 acc[4][4];
#pragma unroll
    for (int mt = 0; mt < 4; ++mt)
#pragma unroll
        for (int nt = 0; nt < 4; ++nt)
            acc[mt][nt] = (f32x4){0.f, 0.f, 0.f, 0.f};

#pragma unroll 2
    for (int kc = 0; kc < 8; ++kc) {
        int koff = kc * 32 + q * 8;
        bf16x8 a[4], b[4];
#pragma unroll
        for (int mt = 0; mt < 4; ++mt)
            a[mt] = *reinterpret_cast<const bf16x8*>(&As[mt * 16 + ln][koff]);
#pragma unroll
        for (int nt = 0; nt < 4; ++nt)
            b[nt] = *reinterpret_cast<const bf16x8*>(Wtb + (size_t)(n0 + nt * 16 + ln) * 256 + koff);
#pragma unroll
        for (int mt = 0; mt < 4; ++mt)
#pragma unroll
            for (int nt = 0; nt < 4; ++nt)
                acc[mt][nt] = __builtin_amdgcn_mfma_f32_16x16x32_bf16(a[mt], b[nt], acc[mt][nt], 0, 0, 0);
    }

    float bv[4];
#pragma unroll
    for (int nt = 0; nt < 4; ++nt) bv[nt] = bias[n0 + nt * 16 + ln];

#pragma unroll
    for (int mt = 0; mt < 4; ++mt) {
#pragma unroll
        for (int r = 0; r < 4; ++r) {
            int row = row0 + mt * 16 + q * 4 + r;
            if (row < N_NODES) {
                unsigned short* po = hb + (size_t)row * CH + n0 + ln;
#pragma unroll
                for (int nt = 0; nt < 4; ++nt)
                    po[nt * 16] = f2bf(acc[mt][nt][r] + bv[nt]);
            }
        }
    }
}

// out[d] = (sum_{e} h[src_e]) / max(deg,1). Bias is inside h; empty sum -> 0
// which matches the reference's deg=0 case. One wave per node, 8-edge unroll
// (8 outstanding 512 B wave-gathers), fp32 accumulate.
__global__ void aggregate_h_k(const unsigned short* __restrict__ hb,
                              const int* __restrict__ edge_src,
                              const int* __restrict__ off, const int* __restrict__ deg,
                              float* __restrict__ out) {
    int wid = threadIdx.x >> 6;
    int lane = threadIdx.x & 63;
    int node = blockIdx.x * 4 + wid;
    int start = __builtin_amdgcn_readfirstlane(off[node]);
    int d     = __builtin_amdgcn_readfirstlane(deg[node]);
    float4 acc[4];
#pragma unroll
    for (int i = 0; i < 4; ++i) acc[i] = make_float4(0.f, 0.f, 0.f, 0.f);
    const unsigned short* hbl = hb + lane * 4;
    const int* es = edge_src + start;
    int e = 0;
    for (; e + 8 <= d; e += 8) {
        int s[8];
#pragma unroll
        for (int i = 0; i < 8; ++i) s[i] = es[e + i];
        ushort4 v[8];
#pragma unroll
        for (int i = 0; i < 8; ++i)
            v[i] = *reinterpret_cast<const ushort4*>(hbl + (size_t)s[i] * CH);
#pragma unroll
        for (int i = 0; i < 8; ++i) {
            acc[i & 3].x += bf2f(v[i].x); acc[i & 3].y += bf2f(v[i].y);
            acc[i & 3].z += bf2f(v[i].z); acc[i & 3].w += bf2f(v[i].w);
        }
    }
    for (; e + 4 <= d; e += 4) {
        int s[4];
#pragma unroll
        for (int i = 0; i < 4; ++i) s[i] = es[e + i];
#pragma unroll
        for (int i = 0; i < 4; ++i) {
            ushort4 v = *reinterpret_cast<const ushort4*>(hbl + (size_t)s[i] * CH);
            acc[i].x += bf2f(v.x); acc[i].y += bf2f(v.y);
            acc[i].z += bf2f(v.z); acc[i].w += bf2f(v.w);
        }
    }
    for (; e < d; ++e) {
        int s0 = es[e];
        ushort4 v = *reinterpret_cast<const ushort4*>(hbl + (size_t)s0 * CH);
        acc[0].x += bf2f(v.x); acc[0].y += bf2f(v.y);
        acc[0].z += bf2f(v.z); acc[0].w += bf2f(v.w);
    }
    acc[0].x += acc[1].x + acc[2].x + acc[3].x;
    acc[0].y += acc[1].y + acc[2].y + acc[3].y;
    acc[0].z += acc[1].z + acc[2].z + acc[3].z;
    acc[0].w += acc[1].w + acc[2].w + acc[3].w;
    float inv = 1.0f / (float)(d > 0 ? d : 1);
    acc[0].x *= inv; acc[0].y *= inv; acc[0].z *= inv; acc[0].w *= inv;
    *reinterpret_cast<float4*>(out + (size_t)node * CH + lane * 4) = acc[0];
}

// ---------------- fallback path (ws too small for hb): fp32 aggregate + in-place gemm
__global__ void aggregate_f32_k(const float* __restrict__ x, const int* __restrict__ edge_src,
                                const int* __restrict__ off, const int* __restrict__ deg,
                                float* __restrict__ m) {
    int wid = threadIdx.x >> 6;
    int lane = threadIdx.x & 63;
    int node = blockIdx.x * 4 + wid;
    int start = off[node];
    int d = deg[node];
    float4 acc0 = make_float4(0.f, 0.f, 0.f, 0.f);
    float4 acc1 = make_float4(0.f, 0.f, 0.f, 0.f);
    const float* xb = x + (size_t)lane * 4;
    int e = 0;
    for (; e + 2 <= d; e += 2) {
        int s0 = edge_src[start + e];
        int s1 = edge_src[start + e + 1];
        const float4 v0 = *reinterpret_cast<const float4*>(xb + (size_t)s0 * CH);
        const float4 v1 = *reinterpret_cast<const float4*>(xb + (size_t)s1 * CH);
        acc0.x += v0.x; acc0.y += v0.y; acc0.z += v0.z; acc0.w += v0.w;
        acc1.x += v1.x; acc1.y += v1.y; acc1.z += v1.z; acc1.w += v1.w;
    }
    if (e < d) {
        int s0 = edge_src[start + e];
        const float4 v0 = *reinterpret_cast<const float4*>(xb + (size_t)s0 * CH);
        acc0.x += v0.x; acc0.y += v0.y; acc0.z += v0.z; acc0.w += v0.w;
    }
    acc0.x += acc1.x; acc0.y += acc1.y; acc0.z += acc1.z; acc0.w += acc1.w;
    float inv = 1.0f / (float)(d > 0 ? d : 1);
    acc0.x *= inv; acc0.y *= inv; acc0.z *= inv; acc0.w *= inv;
    *reinterpret_cast<float4*>(m + (size_t)node * CH + lane * 4) = acc0;
}

__global__ __launch_bounds__(256) void gemm_mfma_k(float* __restrict__ io,
                                                   const unsigned short* __restrict__ Wtb,
                                                   const float* __restrict__ bias,
                                                   const int* __restrict__ deg) {
    __shared__ unsigned short As[64][264];
    int row0 = blockIdx.x * 64;
    int rows = N_NODES - row0;
    if (rows > 64) rows = 64;
    int tid = threadIdx.x;
#pragma unroll
    for (int i = 0; i < 16; ++i) {
        int f = i * 256 + tid;
        int r = f >> 6;
        int c4 = (f & 63) * 4;
        float4 v = make_float4(0.f, 0.f, 0.f, 0.f);
        if (r < rows)
            v = *reinterpret_cast<const float4*>(io + (size_t)(row0 + r) * CH + c4);
        ushort4 o;
        o.x = f2bf(v.x); o.y = f2bf(v.y); o.z = f2bf(v.z); o.w = f2bf(v.w);
        *reinterpret_cast<ushort4*>(&As[r][c4]) = o;
    }
    __syncthreads();
    int wv = tid >> 6;
    int lane = tid & 63;
    int q = lane >> 4;
    int ln = lane & 15;
    int n0 = wv * 64;
    f32x4 acc[4][4];
#pragma unroll
    for (int mt = 0; mt < 4; ++mt)
#pragma unroll
        for (int nt = 0; nt < 4; ++nt)
            acc[mt][nt] = (f32x4){0.f, 0.f, 0.f, 0.f};
#pragma unroll 2
    for (int kc = 0; kc < 8; ++kc) {
        int koff = kc * 32 + q * 8;
        bf16x8 a[4], b[4];
#pragma unroll
        for (int mt = 0; mt < 4; ++mt)
            a[mt] = *reinterpret_cast<const bf16x8*>(&As[mt * 16 + ln][koff]);
#pragma unroll
        for (int nt = 0; nt < 4; ++nt)
            b[nt] = *reinterpret_cast<const bf16x8*>(Wtb + (size_t)(n0 + nt * 16 + ln) * 256 + koff);
#pragma unroll
        for (int mt = 0; mt < 4; ++mt)
#pragma unroll
            for (int nt = 0; nt < 4; ++nt)
                acc[mt][nt] = __builtin_amdgcn_mfma_f32_16x16x32_bf16(a[mt], b[nt], acc[mt][nt], 0, 0, 0);
    }
    float bv[4];
#pragma unroll
    for (int nt = 0; nt < 4; ++nt) bv[nt] = bias[n0 + nt * 16 + ln];
#pragma unroll
    for (int mt = 0; mt < 4; ++mt) {
#pragma unroll
        for (int r = 0; r < 4; ++r) {
            int row = row0 + mt * 16 + q * 4 + r;
            if (row < N_NODES) {
                float bon = (deg[row] > 0) ? 1.f : 0.f;
                float* po = io + (size_t)row * CH + n0 + ln;
#pragma unroll
                for (int nt = 0; nt < 4; ++nt)
                    po[nt * 16] = acc[mt][nt][r] + bv[nt] * bon;
            }
        }
    }
}

extern "C" void kernel_launch(void* const* d_in, const int* in_sizes, int n_in,
                              void* d_out, int out_size, void* d_ws, size_t ws_size,
                              hipStream_t stream) {
    const float* x    = (const float*)d_in[0];
    const int*   src  = (const int*)d_in[1];
    const int*   dst  = (const int*)d_in[2];
    const float* W    = (const float*)d_in[3];
    const float* bias = (const float*)d_in[4];
    float* out = (float*)d_out;

    char* ws = (char*)d_ws;
    int* deg        = (int*)(ws + WS_DEG);
    int* off        = (int*)(ws + WS_OFF);
    int* bcnt       = (int*)(ws + WS_BCNT);
    int* bbase      = (int*)(ws + WS_BBASE);
    int* bcur       = (int*)(ws + WS_BCUR);
    unsigned short* Wtb = (unsigned short*)(ws + WS_WTB);
    int* edge_src   = (int*)(ws + WS_ESRC);
    unsigned* packed = (unsigned*)(ws + WS_PACKED);
    unsigned short* hb = (unsigned short*)(ws + WS_HB);  // aliases packed

    bool use_h = ws_size >= WS_NEED_H;

    hipMemsetAsync(bcnt, 0, NBUCK * sizeof(int), stream);

    hist_k<<<PGRID, 256, 0, stream>>>(dst, bcnt);
    bscan_k<<<1, 256, 0, stream>>>(bcnt, bbase, bcur);
    partition_k<<<PGRID, 256, 0, stream>>>(src, dst, bcur, packed);
    build_k<<<NBUCK_USED, 256, 0, stream>>>(packed, bbase, bcnt, deg, off, edge_src);

    cast_w_k<<<256, 256, 0, stream>>>(W, Wtb);

    if (use_h) {
        // GEMM first (x -> h bf16, bias folded in), then mean-aggregate h.
        gemm_h_k<<<(N_NODES + 63) / 64, 256, 0, stream>>>(x, Wtb, bias, hb);  // after build_k!
        aggregate_h_k<<<N_NODES / 4, 256, 0, stream>>>(hb, edge_src, off, deg, out);
    } else {
        aggregate_f32_k<<<N_NODES / 4, 256, 0, stream>>>(x, edge_src, off, deg, out);
        gemm_mfma_k<<<(N_NODES + 63) / 64, 256, 0, stream>>>(out, Wtb, bias, deg);
    }
}